// Round 9
// baseline (208.218 us; speedup 1.0000x reference)
//
#include <hip/hip_runtime.h>

typedef __bf16 bf16x8 __attribute__((ext_vector_type(8)));
typedef float  f32x4  __attribute__((ext_vector_type(4)));

#define NBAT 16
#define NP   2048
#define ND   64
#define NOUT 128
#define NK   16
#define RT   16            // rows per knn block
#define HSTR 2052          // d2 LDS row stride in halves (4104 B, 8B-aligned)
#define WSTR 132           // W LDS stride (floats)
#define XSTR 68            // x tile LDS stride (floats)

static __device__ __forceinline__ unsigned short f2bf(float f) {
    unsigned u = __float_as_uint(f);
    u += 0x7FFF + ((u >> 16) & 1);      // RNE
    return (unsigned short)(u >> 16);
}
static __device__ __forceinline__ int lanes_below(unsigned long long m) {
    return (int)__builtin_amdgcn_mbcnt_hi((unsigned)(m >> 32),
             __builtin_amdgcn_mbcnt_lo((unsigned)m, 0u));
}
static __device__ __forceinline__ unsigned long long umin64(unsigned long long a, unsigned long long b){ return a < b ? a : b; }
static __device__ __forceinline__ unsigned long long umax64(unsigned long long a, unsigned long long b){ return a < b ? b : a; }

// ascending bitonic sort of 128 u64 keys, element e = slot*64 + lane (rare path)
static __device__ __forceinline__ void bitonic_sort128_u64(unsigned long long &k0,
                                                           unsigned long long &k1, int lane) {
#pragma unroll
    for (int k = 2; k <= 64; k <<= 1) {
#pragma unroll
        for (int j = k >> 1; j >= 1; j >>= 1) {
            bool lower = ((lane & j) == 0);
            bool up0 = (k == 64) ? true  : ((lane & k) == 0);
            bool up1 = (k == 64) ? false : ((lane & k) == 0);
            unsigned long long o0 = __shfl_xor(k0, j, 64);
            k0 = (up0 == lower) ? umin64(k0, o0) : umax64(k0, o0);
            unsigned long long o1 = __shfl_xor(k1, j, 64);
            k1 = (up1 == lower) ? umin64(k1, o1) : umax64(k1, o1);
        }
    }
    { unsigned long long mn = umin64(k0, k1), mx = umax64(k0, k1); k0 = mn; k1 = mx; }
#pragma unroll
    for (int j = 32; j >= 1; j >>= 1) {
        bool lower = ((lane & j) == 0);
        unsigned long long o0 = __shfl_xor(k0, j, 64);
        k0 = lower ? umin64(k0, o0) : umax64(k0, o0);
        unsigned long long o1 = __shfl_xor(k1, j, 64);
        k1 = lower ? umin64(k1, o1) : umax64(k1, o1);
    }
}

// fp64-exact squared distance, rounded to fp32
static __device__ __forceinline__ float
refine_d(const float* __restrict__ x, int gr, int gcbase, int jc) {
    const float* xr = x + (size_t)gr * ND;
    const float* xc = x + (size_t)(gcbase + jc) * ND;
    double s0 = 0.0, s1 = 0.0;
#pragma unroll
    for (int k8 = 0; k8 < 8; ++k8) {
        float4 a = *(const float4*)(xr + k8 * 8);
        float4 b = *(const float4*)(xc + k8 * 8);
        float4 a2 = *(const float4*)(xr + k8 * 8 + 4);
        float4 b2 = *(const float4*)(xc + k8 * 8 + 4);
        double e0 = (double)a.x - (double)b.x;
        double e1 = (double)a.y - (double)b.y;
        double e2 = (double)a.z - (double)b.z;
        double e3 = (double)a.w - (double)b.w;
        s0 = fma(e0, e0, s0); s0 = fma(e1, e1, s0);
        s0 = fma(e2, e2, s0); s0 = fma(e3, e3, s0);
        double f0 = (double)a2.x - (double)b2.x;
        double f1 = (double)a2.y - (double)b2.y;
        double f2 = (double)a2.z - (double)b2.z;
        double f3 = (double)a2.w - (double)b2.w;
        s1 = fma(f0, f0, s1); s1 = fma(f1, f1, s1);
        s1 = fma(f2, f2, s1); s1 = fma(f3, f3, s1);
    }
    return (float)(s0 + s1);
}

// ---------------------------------------------------------------------------
// prep: sq (fp64-acc), xb16 (bf16 copy of x), U=(W1-W2)x+b, V=W2x  (fp32)
// grid 2048 x 256 (16 rows/block)
// ---------------------------------------------------------------------------
__global__ void __launch_bounds__(256, 1)
prep_k(const float* __restrict__ x,     // [32768][64]
       const float* __restrict__ W,     // [128][128]  (cols 0..63 = W1, 64..127 = W2)
       const float* __restrict__ bias,  // [128]
       float* __restrict__ sq, float* __restrict__ U,
       float* __restrict__ V,  unsigned short* __restrict__ xb16)
{
    __shared__ float Wl[128 * WSTR];
    __shared__ float xl[16 * XSTR];
    const int blk = blockIdx.x, tid = threadIdx.x;
    const int R0 = blk * 16;

    // stage W (4096 float4)
    for (int f = tid; f < 4096; f += 256) {
        int row = f >> 5, c4 = f & 31;
        float4 v = *(const float4*)(W + row * 128 + c4 * 4);
        *(float4*)(Wl + row * WSTR + c4 * 4) = v;
    }
    // stage x tile (256 float4)
    {
        int r = tid >> 4, c4 = tid & 15;
        float4 v = *(const float4*)(x + (size_t)(R0 + r) * ND + c4 * 4);
        *(float4*)(xl + r * XSTR + c4 * 4) = v;
    }
    __syncthreads();

    // bf16 copy
    {
        int r = tid >> 4, c = (tid & 15) * 4;
        float4 v = *(const float4*)(xl + r * XSTR + c);
        ushort4 hb;
        hb.x = f2bf(v.x); hb.y = f2bf(v.y); hb.z = f2bf(v.z); hb.w = f2bf(v.w);
        *(ushort4*)(xb16 + (size_t)(R0 + r) * ND + c) = hb;
    }
    // sq with fp64 accumulation (threads 0..127, 8 lanes per row)
    if (tid < 128) {
        int r = tid >> 3, seg = tid & 7;
        float4 a = *(const float4*)(xl + r * XSTR + seg * 8);
        float4 b = *(const float4*)(xl + r * XSTR + seg * 8 + 4);
        double s = (double)a.x * a.x + (double)a.y * a.y +
                   (double)a.z * a.z + (double)a.w * a.w +
                   (double)b.x * b.x + (double)b.y * b.y +
                   (double)b.z * b.z + (double)b.w * b.w;
        s += __shfl_xor(s, 1, 64);
        s += __shfl_xor(s, 2, 64);
        s += __shfl_xor(s, 4, 64);
        if (seg == 0) sq[R0 + r] = (float)s;
    }

    // U/V
    {
        const int r = tid >> 4, g = tid & 15;
        float accP[8], accV[8];
#pragma unroll
        for (int m = 0; m < 8; ++m) { accP[m] = 0.f; accV[m] = 0.f; }
#pragma unroll
        for (int k4 = 0; k4 < 16; ++k4) {
            float4 xv = *(const float4*)(xl + r * XSTR + k4 * 4);
#pragma unroll
            for (int m = 0; m < 8; ++m) {
                const float* wp = Wl + (g + 16 * m) * WSTR + k4 * 4;
                float4 w1 = *(const float4*)(wp);
                float4 w2 = *(const float4*)(wp + 64);
                accP[m] = fmaf(xv.x, w1.x, accP[m]); accP[m] = fmaf(xv.y, w1.y, accP[m]);
                accP[m] = fmaf(xv.z, w1.z, accP[m]); accP[m] = fmaf(xv.w, w1.w, accP[m]);
                accV[m] = fmaf(xv.x, w2.x, accV[m]); accV[m] = fmaf(xv.y, w2.y, accV[m]);
                accV[m] = fmaf(xv.z, w2.z, accV[m]); accV[m] = fmaf(xv.w, w2.w, accV[m]);
            }
        }
        const size_t gr = (size_t)(R0 + r);
#pragma unroll
        for (int m = 0; m < 8; ++m) {
            int o = g + 16 * m;
            U[gr * NOUT + o] = accP[m] - accV[m] + bias[o];
            V[gr * NOUT + o] = accV[m];
        }
    }
}

// ---------------------------------------------------------------------------
// knn + aggregate. grid 2048 x 512 (8 waves), RT=16, 2 blocks/CU.
// Phase 1: bf16 MFMA Gram -> fp16 d2 tile (66 KB LDS).
// Phase 2 (DS-light): tau via 16-rd ballot radix (0 DS); scan compaction;
//   fp64 refine; winner set via 31-rd ballot radix on fp32 bits (0 DS);
//   V-gather via s_ff1 + v_readlane (0 DS). sort128_u64 fallback if >64.
// ---------------------------------------------------------------------------
__global__ void __launch_bounds__(512, 2)
knn_k(const float* __restrict__ x,             // [32768][64] fp32 (refine)
      const unsigned short* __restrict__ xb16, // [32768][64] bf16
      const float* __restrict__ sq,
      const float* __restrict__ U,
      const float* __restrict__ V,
      float* __restrict__ out)
{
    extern __shared__ __align__(16) unsigned char smem[];
    unsigned short* d2h = (unsigned short*)smem;   // [RT][HSTR] halves
    __shared__ unsigned short cbuf[8][128];

    // XCD-aware decode: q%8 = XCD; each XCD gets 2 full batches
    const int q   = blockIdx.x;
    const int xcd = q & 7;
    const int k_  = q >> 3;               // 0..255
    const int bb  = xcd * 2 + (k_ >> 7);  // batch
    const int rt  = k_ & 127;             // row tile within batch
    const int R0l = rt * RT;
    const int R0g = bb * NP + R0l;
    const int tid = threadIdx.x;
    const int w   = tid >> 6;             // 0..7
    const int l   = tid & 63;
    const int l15 = l & 15, lg = l >> 4, kc = lg * 8;

    // N-operand fragments: the 16 block rows
    const unsigned short* nr = xb16 + (size_t)(R0g + l15) * ND + kc;
    bf16x8 n0 = *(const bf16x8*)(nr);
    bf16x8 n1 = *(const bf16x8*)(nr + 32);
    const float sqrow = sq[R0g + l15];

    const unsigned short* xbb = xb16 + (size_t)bb * NP * ND;
    const float* sqb = sq + bb * NP;

    // ---- Phase 1: MFMA Gram -> fp16 d2 in LDS (16 col-tiles per wave) ----
#pragma unroll 2
    for (int t = 0; t < 16; ++t) {
        const int cb = (w * 16 + t) * 16;
        const unsigned short* ar = xbb + (size_t)(cb + l15) * ND + kc;
        bf16x8 a0 = *(const bf16x8*)(ar);
        bf16x8 a1 = *(const bf16x8*)(ar + 32);
        f32x4 acc = {0.f, 0.f, 0.f, 0.f};
        acc = __builtin_amdgcn_mfma_f32_16x16x32_bf16(a0, n0, acc, 0, 0, 0);
        acc = __builtin_amdgcn_mfma_f32_16x16x32_bf16(a1, n1, acc, 0, 0, 0);
        // D[batch col][block row]: lane holds block row = l15, cols jb4..jb4+3
        const int jb4 = cb + lg * 4;
        float4 sq4 = *(const float4*)(sqb + jb4);
        unsigned short hh[4];
#pragma unroll
        for (int i = 0; i < 4; ++i) {
            float sqc = (i == 0) ? sq4.x : (i == 1) ? sq4.y : (i == 2) ? sq4.z : sq4.w;
            float d2 = fmaxf(fmaf(-2.f, acc[i], sqrow + sqc), 0.f);
            unsigned short h = __builtin_bit_cast(unsigned short, (_Float16)d2);
            if (R0l + l15 == jb4 + i) h = 0x7C00;   // self -> +inf
            hh[i] = h;
        }
        ushort4 hv; hv.x = hh[0]; hv.y = hh[1]; hv.z = hh[2]; hv.w = hh[3];
        *(ushort4*)(d2h + (size_t)l15 * HSTR + jb4) = hv;
    }
    __syncthreads();

    // ---- Phase 2: per-wave 2 rows ----
    const int gcbase = bb * NP;
#pragma unroll 1
    for (int rr = 0; rr < 2; ++rr) {
        const int r  = w * 2 + rr;
        const int gr = R0g + r;
        const unsigned short* rowp = d2h + (size_t)r * HSTR;

        // load 32 fp16 values; slot (s,i) <-> col j = 256*s + 4*l + i
        unsigned int h[32];
#pragma unroll
        for (int s = 0; s < 8; ++s) {
            ushort4 hv = *(const ushort4*)(rowp + (s * 64 + l) * 4);
            h[s*4+0] = hv.x; h[s*4+1] = hv.y; h[s*4+2] = hv.z; h[s*4+3] = hv.w;
        }
        unsigned int mnh = h[0];
#pragma unroll
        for (int i = 1; i < 32; ++i) mnh = (h[i] < mnh) ? h[i] : mnh;

        // tau = 16th smallest of the 64 lane-minima: ballot radix (0 DS ops)
        unsigned int t16 = 0;
#pragma unroll
        for (int b = 15; b >= 0; --b) {
            unsigned int cand = t16 | (1u << b);
            int c = __popcll(__ballot(mnh < cand));
            if (c < 16) t16 = cand;
        }
        // widen by +1.0 ABSOLUTE (bf16 Gram noise, 11 sigma) + 1 ulp
        float tf = (float)__builtin_bit_cast(_Float16, (unsigned short)t16) + 1.0f;
        unsigned int tauh =
            (unsigned int)__builtin_bit_cast(unsigned short, (_Float16)tf) + 1u;

        // per-lane survivor pack (slot ids, 5 bits each, up to 4)
        unsigned int packed = 0; int cnt = 0;
#pragma unroll
        for (int i = 0; i < 32; ++i) {
            if (h[i] <= tauh) {
                if (cnt < 4) packed |= (unsigned)i << (5 * cnt);
                ++cnt;
            }
        }
        bool ovf = (__ballot(cnt > 4) != 0ull);   // wave-uniform

        cbuf[w][l]      = 0xFFFF;
        cbuf[w][64 + l] = 0xFFFF;
        int total;
        if (!ovf) {
            // exclusive scan of cnt (6 shfl_up)
            int inc = cnt;
#pragma unroll
            for (int off = 1; off < 64; off <<= 1) {
                int nv = __shfl_up(inc, off, 64);
                if (l >= off) inc += nv;
            }
            int excl = inc - cnt;
            total = __shfl(inc, 63, 64);
#pragma unroll
            for (int kk = 0; kk < 4; ++kk) {
                if (kk < cnt && excl + kk < 128) {
                    int slot = (packed >> (5 * kk)) & 31;
                    cbuf[w][excl + kk] =
                        (unsigned short)(256 * (slot >> 2) + 4 * l + (slot & 3));
                }
            }
        } else {
            // rare slow path: serial ballot compaction
            int base = 0;
#pragma unroll 1
            for (int i = 0; i < 32; ++i) {
                bool pred = (h[i] <= tauh);
                unsigned long long m = __ballot(pred);
                int pos = base + lanes_below(m);
                if (pred && pos < 128)
                    cbuf[w][pos] = (unsigned short)(256 * (i >> 2) + 4 * l + (i & 3));
                base += __popcll(m);
            }
            total = base;
        }
        asm volatile("s_waitcnt lgkmcnt(0)" ::: "memory");
        __builtin_amdgcn_sched_barrier(0);

        const float* Vb = V + (size_t)bb * NP * NOUT;
        float mv0 = -1e30f, mv1 = -1e30f;

        int jc = cbuf[w][l];
        if (total <= 64) {
            // refine my candidate (if any)
            unsigned int dbits = 0xFFFFFFFFu;
            if (jc != 0xFFFF)
                dbits = __float_as_uint(refine_d(x, gr, gcbase, jc));

            // T = 16th smallest refined value: 31-round ballot radix (0 DS)
            unsigned int T = 0;
#pragma unroll
            for (int b = 30; b >= 0; --b) {
                unsigned int cand = T | (1u << b);
                int c = __popcll(__ballot(dbits < cand));
                if (c < 16) T = cand;
            }
            unsigned long long less_m = __ballot(dbits < T);
            int c_less = __popcll(less_m);
            int need = 16 - c_less;
            unsigned long long tie_m = __ballot(dbits == T);
            bool tie_win = (dbits == T) && (lanes_below(tie_m) < need);
            unsigned long long win_m = less_m | __ballot(tie_win);

            // V-gather via scalar ff1 + readlane (0 DS)
            unsigned long long m = win_m;
#pragma unroll 1
            for (int n = 0; n < NK; ++n) {
                if (!m) break;
                int ln = __ffsll((long long)m) - 1;
                m &= (m - 1);
                int jn = __builtin_amdgcn_readlane(jc, ln);
                float2 vv = *(const float2*)(Vb + (size_t)jn * NOUT + (l << 1));
                mv0 = fmaxf(mv0, vv.x);
                mv1 = fmaxf(mv1, vv.y);
            }
        } else {
            // rare fallback: full sort of up to 128 refined keys
            int jc1 = cbuf[w][64 + l];
            unsigned long long rk0 = (jc != 0xFFFF)
                ? ((((unsigned long long)__float_as_uint(refine_d(x, gr, gcbase, jc))) << 11) | (unsigned)jc)
                : ~0ull;
            unsigned long long rk1 = (jc1 != 0xFFFF)
                ? ((((unsigned long long)__float_as_uint(refine_d(x, gr, gcbase, jc1))) << 11) | (unsigned)jc1)
                : ~0ull;
            bitonic_sort128_u64(rk0, rk1, l);
            int nbr = (int)(rk0 & 2047u);
#pragma unroll
            for (int n = 0; n < NK; ++n) {
                int jn = __builtin_amdgcn_readlane(nbr, n);
                float2 vv = *(const float2*)(Vb + (size_t)jn * NOUT + (l << 1));
                mv0 = fmaxf(mv0, vv.x);
                mv1 = fmaxf(mv1, vv.y);
            }
        }

        float2 uu = *(const float2*)(U + (size_t)gr * NOUT + (l << 1));
        float2 ov;
        ov.x = fmaxf(uu.x + mv0, 0.f);
        ov.y = fmaxf(uu.y + mv1, 0.f);
        *(float2*)(out + (size_t)gr * NOUT + (l << 1)) = ov;
    }
}

extern "C" void kernel_launch(void* const* d_in, const int* in_sizes, int n_in,
                              void* d_out, int out_size, void* d_ws, size_t ws_size,
                              hipStream_t stream) {
    const float* x    = (const float*)d_in[0];   // fp32 [32768][64]
    // d_in[1] = pos (unused), d_in[2] = batch (unused; uniform sorted segments)
    const float* W    = (const float*)d_in[3];   // fp32 [128][128]
    const float* bias = (const float*)d_in[4];   // fp32 [128]
    float* out = (float*)d_out;                  // fp32 [32768][128]

    float* sq = (float*)d_ws;                               // 32768 f32
    float* U  = sq + NBAT * NP;                             // 4.19M f32
    float* V  = U  + (size_t)NBAT * NP * NOUT;              // 4.19M f32
    unsigned short* xb16 = (unsigned short*)(V + (size_t)NBAT * NP * NOUT);

    prep_k<<<2048, 256, 0, stream>>>(x, W, bias, sq, U, V, xb16);

    const int lds_bytes = RT * HSTR * 2;                    // 65,664 B
    (void)hipFuncSetAttribute((const void*)knn_k,
                        hipFuncAttributeMaxDynamicSharedMemorySize, lds_bytes);
    knn_k<<<2048, 512, lds_bytes, stream>>>(x, xb16, sq, U, V, out);
}

// Round 10
// 180.595 us; speedup vs baseline: 1.1530x; 1.1530x over previous
//
#include <hip/hip_runtime.h>

typedef __bf16 bf16x8 __attribute__((ext_vector_type(8)));
typedef float  f32x4  __attribute__((ext_vector_type(4)));

#define NBAT 16
#define NP   2048
#define ND   64
#define NOUT 128
#define NK   16
#define RT   16            // rows per knn block
#define HSTR 2052          // d2 LDS row stride in halves (4104 B, 8B-aligned)

static __device__ __forceinline__ unsigned short f2bf(float f) {
    unsigned u = __float_as_uint(f);
    u += 0x7FFF + ((u >> 16) & 1);      // RNE
    return (unsigned short)(u >> 16);
}
static __device__ __forceinline__ int lanes_below(unsigned long long m) {
    return (int)__builtin_amdgcn_mbcnt_hi((unsigned)(m >> 32),
             __builtin_amdgcn_mbcnt_lo((unsigned)m, 0u));
}
static __device__ __forceinline__ unsigned long long umin64(unsigned long long a, unsigned long long b){ return a < b ? a : b; }
static __device__ __forceinline__ unsigned long long umax64(unsigned long long a, unsigned long long b){ return a < b ? b : a; }

// ascending bitonic sort of 128 u64 keys, element e = slot*64 + lane (rare path)
static __device__ __forceinline__ void bitonic_sort128_u64(unsigned long long &k0,
                                                           unsigned long long &k1, int lane) {
#pragma unroll
    for (int k = 2; k <= 64; k <<= 1) {
#pragma unroll
        for (int j = k >> 1; j >= 1; j >>= 1) {
            bool lower = ((lane & j) == 0);
            bool up0 = (k == 64) ? true  : ((lane & k) == 0);
            bool up1 = (k == 64) ? false : ((lane & k) == 0);
            unsigned long long o0 = __shfl_xor(k0, j, 64);
            k0 = (up0 == lower) ? umin64(k0, o0) : umax64(k0, o0);
            unsigned long long o1 = __shfl_xor(k1, j, 64);
            k1 = (up1 == lower) ? umin64(k1, o1) : umax64(k1, o1);
        }
    }
    { unsigned long long mn = umin64(k0, k1), mx = umax64(k0, k1); k0 = mn; k1 = mx; }
#pragma unroll
    for (int j = 32; j >= 1; j >>= 1) {
        bool lower = ((lane & j) == 0);
        unsigned long long o0 = __shfl_xor(k0, j, 64);
        k0 = lower ? umin64(k0, o0) : umax64(k0, o0);
        unsigned long long o1 = __shfl_xor(k1, j, 64);
        k1 = lower ? umin64(k1, o1) : umax64(k1, o1);
    }
}

// fp64-exact squared distance, rounded to fp32
static __device__ __forceinline__ float
refine_d(const float* __restrict__ x, int gr, int gcbase, int jc) {
    const float* xr = x + (size_t)gr * ND;
    const float* xc = x + (size_t)(gcbase + jc) * ND;
    double s0 = 0.0, s1 = 0.0;
#pragma unroll
    for (int k8 = 0; k8 < 8; ++k8) {
        float4 a = *(const float4*)(xr + k8 * 8);
        float4 b = *(const float4*)(xc + k8 * 8);
        float4 a2 = *(const float4*)(xr + k8 * 8 + 4);
        float4 b2 = *(const float4*)(xc + k8 * 8 + 4);
        double e0 = (double)a.x - (double)b.x;
        double e1 = (double)a.y - (double)b.y;
        double e2 = (double)a.z - (double)b.z;
        double e3 = (double)a.w - (double)b.w;
        s0 = fma(e0, e0, s0); s0 = fma(e1, e1, s0);
        s0 = fma(e2, e2, s0); s0 = fma(e3, e3, s0);
        double f0 = (double)a2.x - (double)b2.x;
        double f1 = (double)a2.y - (double)b2.y;
        double f2 = (double)a2.z - (double)b2.z;
        double f3 = (double)a2.w - (double)b2.w;
        s1 = fma(f0, f0, s1); s1 = fma(f1, f1, s1);
        s1 = fma(f2, f2, s1); s1 = fma(f3, f3, s1);
    }
    return (float)(s0 + s1);
}

// split fp32 x8 -> hi/lo bf16x8 (hi = RNE(f); lo = RNE(f - hi); f-hi exact)
static __device__ __forceinline__ void cvt_hilo(const float* __restrict__ p,
                                                bf16x8 &hi, bf16x8 &lo) {
    float4 a = *(const float4*)p, b = *(const float4*)(p + 4);
    float f[8] = {a.x, a.y, a.z, a.w, b.x, b.y, b.z, b.w};
#pragma unroll
    for (int i = 0; i < 8; ++i) {
        __bf16 h = (__bf16)f[i];
        hi[i] = h;
        lo[i] = (__bf16)(f[i] - (float)h);
    }
}

// ---------------------------------------------------------------------------
// prep (LDS-free, MFMA): sq (fp64-acc), xb16 (bf16 copy), U=(W1-W2)x+b, V=W2x.
// U/V via 3-term hi/lo bf16 MFMA (error ~5e-5). grid 2048 x 256.
// MFMA mapping (validated in knn): mfma(A,B): lane l acc[i] = A_row[lg*4+i] . B_row[l15],
// with both frags loaded as row = l15, cols lg*8..+7 per K-tile.
// ---------------------------------------------------------------------------
__global__ void __launch_bounds__(256)
prep_k(const float* __restrict__ x,     // [32768][64]
       const float* __restrict__ W,     // [128][128] (cols 0..63 = W1, 64..127 = W2)
       const float* __restrict__ bias,  // [128]
       float* __restrict__ sq, float* __restrict__ U,
       float* __restrict__ V,  unsigned short* __restrict__ xb16)
{
    const int blk = blockIdx.x, tid = threadIdx.x;
    const int R0 = blk * 16;
    const int w  = tid >> 6, l = tid & 63;
    const int l15 = l & 15, lg = l >> 4, kc = lg * 8;

    // bf16 copy of x (for knn Gram)
    {
        int r = tid >> 4, c = (tid & 15) * 4;
        float4 v = *(const float4*)(x + (size_t)(R0 + r) * ND + c);
        ushort4 hb;
        hb.x = f2bf(v.x); hb.y = f2bf(v.y); hb.z = f2bf(v.z); hb.w = f2bf(v.w);
        *(ushort4*)(xb16 + (size_t)(R0 + r) * ND + c) = hb;
    }
    // sq with fp64 accumulation (threads 0..127, 8 lanes per row)
    if (tid < 128) {
        int r = tid >> 3, seg = tid & 7;
        const float* p = x + (size_t)(R0 + r) * ND + seg * 8;
        float4 a = *(const float4*)(p);
        float4 b = *(const float4*)(p + 4);
        double s = (double)a.x * a.x + (double)a.y * a.y +
                   (double)a.z * a.z + (double)a.w * a.w +
                   (double)b.x * b.x + (double)b.y * b.y +
                   (double)b.z * b.z + (double)b.w * b.w;
        s += __shfl_xor(s, 1, 64);
        s += __shfl_xor(s, 2, 64);
        s += __shfl_xor(s, 4, 64);
        if (seg == 0) sq[R0 + r] = (float)s;
    }

    // B-frags: X rows hi/lo, K-tiles 0 and 1
    const float* xr = x + (size_t)(R0 + l15) * ND + kc;
    bf16x8 bh0, bl0, bh1, bl1;
    cvt_hilo(xr,      bh0, bl0);
    cvt_hilo(xr + 32, bh1, bl1);

    // each wave: o-tiles {w, w+4}
#pragma unroll
    for (int tt = 0; tt < 2; ++tt) {
        const int ot = w + tt * 4;
        const float* wb = W + (size_t)(ot * 16 + l15) * (2 * ND) + kc;
        f32x4 accP = {0.f, 0.f, 0.f, 0.f};
        f32x4 accV = {0.f, 0.f, 0.f, 0.f};
        bf16x8 ah, al;
        // W1, K-tile 0/1
        cvt_hilo(wb, ah, al);
        accP = __builtin_amdgcn_mfma_f32_16x16x32_bf16(ah, bh0, accP, 0, 0, 0);
        accP = __builtin_amdgcn_mfma_f32_16x16x32_bf16(ah, bl0, accP, 0, 0, 0);
        accP = __builtin_amdgcn_mfma_f32_16x16x32_bf16(al, bh0, accP, 0, 0, 0);
        cvt_hilo(wb + 32, ah, al);
        accP = __builtin_amdgcn_mfma_f32_16x16x32_bf16(ah, bh1, accP, 0, 0, 0);
        accP = __builtin_amdgcn_mfma_f32_16x16x32_bf16(ah, bl1, accP, 0, 0, 0);
        accP = __builtin_amdgcn_mfma_f32_16x16x32_bf16(al, bh1, accP, 0, 0, 0);
        // W2, K-tile 0/1
        cvt_hilo(wb + 64, ah, al);
        accV = __builtin_amdgcn_mfma_f32_16x16x32_bf16(ah, bh0, accV, 0, 0, 0);
        accV = __builtin_amdgcn_mfma_f32_16x16x32_bf16(ah, bl0, accV, 0, 0, 0);
        accV = __builtin_amdgcn_mfma_f32_16x16x32_bf16(al, bh0, accV, 0, 0, 0);
        cvt_hilo(wb + 96, ah, al);
        accV = __builtin_amdgcn_mfma_f32_16x16x32_bf16(ah, bh1, accV, 0, 0, 0);
        accV = __builtin_amdgcn_mfma_f32_16x16x32_bf16(ah, bl1, accV, 0, 0, 0);
        accV = __builtin_amdgcn_mfma_f32_16x16x32_bf16(al, bh1, accV, 0, 0, 0);

        // lane holds row = R0+l15, channels o = ot*16 + lg*4 + i
        const int o0 = ot * 16 + lg * 4;
        float4 bo = *(const float4*)(bias + o0);
        float4 uu, vv;
        uu.x = accP[0] - accV[0] + bo.x;  vv.x = accV[0];
        uu.y = accP[1] - accV[1] + bo.y;  vv.y = accV[1];
        uu.z = accP[2] - accV[2] + bo.z;  vv.z = accV[2];
        uu.w = accP[3] - accV[3] + bo.w;  vv.w = accV[3];
        float* up = U + (size_t)(R0 + l15) * NOUT + o0;
        float* vp = V + (size_t)(R0 + l15) * NOUT + o0;
        *(float4*)up = uu;
        *(float4*)vp = vv;
    }
}

// ---------------------------------------------------------------------------
// knn + aggregate. grid 2048 x 512 (8 waves), RT=16, 2 blocks/CU.
// Phase 1: bf16 MFMA Gram -> fp16 d2 tile (66 KB LDS), unroll 4.
// Phase 2: tau via 16-rd ballot radix; scan compaction; fp64 refine;
//   T via 31-rd ballot radix; exact-16 winner mask; SALU-ffs gather with all
//   16 loads in flight. Fallback to sort128_u64 if >64 survivors OR
//   ambiguous fp32 tie at the boundary (exact top_k semantics).
// ---------------------------------------------------------------------------
__global__ void __launch_bounds__(512, 2)
knn_k(const float* __restrict__ x,             // [32768][64] fp32 (refine)
      const unsigned short* __restrict__ xb16, // [32768][64] bf16
      const float* __restrict__ sq,
      const float* __restrict__ U,
      const float* __restrict__ V,
      float* __restrict__ out)
{
    extern __shared__ __align__(16) unsigned char smem[];
    unsigned short* d2h = (unsigned short*)smem;   // [RT][HSTR] halves
    __shared__ unsigned short cbuf[8][128];

    // XCD-aware decode: q%8 = XCD; each XCD gets 2 full batches
    const int q   = blockIdx.x;
    const int xcd = q & 7;
    const int k_  = q >> 3;               // 0..255
    const int bb  = xcd * 2 + (k_ >> 7);  // batch
    const int rt  = k_ & 127;             // row tile within batch
    const int R0l = rt * RT;
    const int R0g = bb * NP + R0l;
    const int tid = threadIdx.x;
    const int w   = tid >> 6;             // 0..7
    const int l   = tid & 63;
    const int l15 = l & 15, lg = l >> 4, kc = lg * 8;

    // N-operand fragments: the 16 block rows
    const unsigned short* nr = xb16 + (size_t)(R0g + l15) * ND + kc;
    bf16x8 n0 = *(const bf16x8*)(nr);
    bf16x8 n1 = *(const bf16x8*)(nr + 32);
    const float sqrow = sq[R0g + l15];

    const unsigned short* xbb = xb16 + (size_t)bb * NP * ND;
    const float* sqb = sq + bb * NP;

    // ---- Phase 1: MFMA Gram -> fp16 d2 in LDS (16 col-tiles per wave) ----
#pragma unroll 4
    for (int t = 0; t < 16; ++t) {
        const int cb = (w * 16 + t) * 16;
        const unsigned short* ar = xbb + (size_t)(cb + l15) * ND + kc;
        bf16x8 a0 = *(const bf16x8*)(ar);
        bf16x8 a1 = *(const bf16x8*)(ar + 32);
        f32x4 acc = {0.f, 0.f, 0.f, 0.f};
        acc = __builtin_amdgcn_mfma_f32_16x16x32_bf16(a0, n0, acc, 0, 0, 0);
        acc = __builtin_amdgcn_mfma_f32_16x16x32_bf16(a1, n1, acc, 0, 0, 0);
        // D[batch col][block row]: lane holds block row = l15, cols jb4..jb4+3
        const int jb4 = cb + lg * 4;
        float4 sq4 = *(const float4*)(sqb + jb4);
        unsigned short hh[4];
#pragma unroll
        for (int i = 0; i < 4; ++i) {
            float sqc = (i == 0) ? sq4.x : (i == 1) ? sq4.y : (i == 2) ? sq4.z : sq4.w;
            float d2 = fmaxf(fmaf(-2.f, acc[i], sqrow + sqc), 0.f);
            unsigned short h = __builtin_bit_cast(unsigned short, (_Float16)d2);
            if (R0l + l15 == jb4 + i) h = 0x7C00;   // self -> +inf
            hh[i] = h;
        }
        ushort4 hv; hv.x = hh[0]; hv.y = hh[1]; hv.z = hh[2]; hv.w = hh[3];
        *(ushort4*)(d2h + (size_t)l15 * HSTR + jb4) = hv;
    }
    __syncthreads();

    // ---- Phase 2: per-wave 2 rows ----
    const int gcbase = bb * NP;
#pragma unroll 1
    for (int rr = 0; rr < 2; ++rr) {
        const int r  = w * 2 + rr;
        const int gr = R0g + r;
        const unsigned short* rowp = d2h + (size_t)r * HSTR;

        // load 32 fp16 values; slot (s,i) <-> col j = 256*s + 4*l + i
        unsigned int h[32];
#pragma unroll
        for (int s = 0; s < 8; ++s) {
            ushort4 hv = *(const ushort4*)(rowp + (s * 64 + l) * 4);
            h[s*4+0] = hv.x; h[s*4+1] = hv.y; h[s*4+2] = hv.z; h[s*4+3] = hv.w;
        }
        unsigned int mnh = h[0];
#pragma unroll
        for (int i = 1; i < 32; ++i) mnh = (h[i] < mnh) ? h[i] : mnh;

        // tau = 16th smallest of the 64 lane-minima: ballot radix (0 DS ops)
        unsigned int t16 = 0;
#pragma unroll
        for (int b = 15; b >= 0; --b) {
            unsigned int cand = t16 | (1u << b);
            int c = __popcll(__ballot(mnh < cand));
            if (c < 16) t16 = cand;
        }
        // widen by +1.0 ABSOLUTE (bf16 Gram noise, 11 sigma) + 1 ulp
        float tf = (float)__builtin_bit_cast(_Float16, (unsigned short)t16) + 1.0f;
        unsigned int tauh =
            (unsigned int)__builtin_bit_cast(unsigned short, (_Float16)tf) + 1u;

        // per-lane survivor pack (slot ids, 5 bits each, up to 4)
        unsigned int packed = 0; int cnt = 0;
#pragma unroll
        for (int i = 0; i < 32; ++i) {
            if (h[i] <= tauh) {
                if (cnt < 4) packed |= (unsigned)i << (5 * cnt);
                ++cnt;
            }
        }
        bool ovf = (__ballot(cnt > 4) != 0ull);   // wave-uniform

        cbuf[w][l]      = 0xFFFF;
        cbuf[w][64 + l] = 0xFFFF;
        int total;
        if (!ovf) {
            // exclusive scan of cnt (6 shfl_up)
            int inc = cnt;
#pragma unroll
            for (int off = 1; off < 64; off <<= 1) {
                int nv = __shfl_up(inc, off, 64);
                if (l >= off) inc += nv;
            }
            int excl = inc - cnt;
            total = __shfl(inc, 63, 64);
#pragma unroll
            for (int kk = 0; kk < 4; ++kk) {
                if (kk < cnt && excl + kk < 128) {
                    int slot = (packed >> (5 * kk)) & 31;
                    cbuf[w][excl + kk] =
                        (unsigned short)(256 * (slot >> 2) + 4 * l + (slot & 3));
                }
            }
        } else {
            // rare slow path: serial ballot compaction
            int base = 0;
#pragma unroll 1
            for (int i = 0; i < 32; ++i) {
                bool pred = (h[i] <= tauh);
                unsigned long long m = __ballot(pred);
                int pos = base + lanes_below(m);
                if (pred && pos < 128)
                    cbuf[w][pos] = (unsigned short)(256 * (i >> 2) + 4 * l + (i & 3));
                base += __popcll(m);
            }
            total = base;
        }
        asm volatile("s_waitcnt lgkmcnt(0)" ::: "memory");
        __builtin_amdgcn_sched_barrier(0);

        const float* Vb = V + (size_t)bb * NP * NOUT;
        float mv0 = -1e30f, mv1 = -1e30f;
        int jc = cbuf[w][l];

        bool fast = (total <= 64);
        unsigned long long win_m = 0ull;
        if (fast) {
            unsigned int dbits = 0xFFFFFFFFu;
            if (jc != 0xFFFF)
                dbits = __float_as_uint(refine_d(x, gr, gcbase, jc));

            // T = 16th smallest refined value: 31-round ballot radix (0 DS)
            unsigned int T = 0;
#pragma unroll
            for (int b = 30; b >= 0; --b) {
                unsigned int cand = T | (1u << b);
                int c = __popcll(__ballot(dbits < cand));
                if (c < 16) T = cand;
            }
            unsigned long long less_m = __ballot(dbits < T);
            int c_less = __popcll(less_m);
            int need = 16 - c_less;
            unsigned long long tie_m = __ballot(dbits == T);
            if (__popcll(tie_m) == need) {
                win_m = less_m | tie_m;           // exactly 16, unambiguous
            } else {
                fast = false;                      // ambiguous fp32 tie: exact path
            }
        }

        if (fast) {
            // extract the 16 winner indices (SALU ffs chain), then 16
            // independent loads -> one wait -> max tree
            int jns[NK];
            unsigned long long mm = win_m;
#pragma unroll
            for (int n = 0; n < NK; ++n) {
                int ln = __ffsll((long long)mm) - 1;
                jns[n] = __builtin_amdgcn_readlane(jc, ln);
                mm &= mm - 1;
            }
            float2 vv[NK];
#pragma unroll
            for (int n = 0; n < NK; ++n)
                vv[n] = *(const float2*)(Vb + (size_t)jns[n] * NOUT + (l << 1));
#pragma unroll
            for (int n = 0; n < NK; ++n) {
                mv0 = fmaxf(mv0, vv[n].x);
                mv1 = fmaxf(mv1, vv[n].y);
            }
        } else {
            // exact fallback: sort refined keys with index tiebreak
            int jc1 = cbuf[w][64 + l];
            unsigned long long rk0 = (jc != 0xFFFF)
                ? ((((unsigned long long)__float_as_uint(refine_d(x, gr, gcbase, jc))) << 11) | (unsigned)jc)
                : ~0ull;
            unsigned long long rk1 = (jc1 != 0xFFFF)
                ? ((((unsigned long long)__float_as_uint(refine_d(x, gr, gcbase, jc1))) << 11) | (unsigned)jc1)
                : ~0ull;
            bitonic_sort128_u64(rk0, rk1, l);
            int nbr = (int)(rk0 & 2047u);
            int jns[NK];
#pragma unroll
            for (int n = 0; n < NK; ++n)
                jns[n] = __builtin_amdgcn_readlane(nbr, n);
            float2 vv[NK];
#pragma unroll
            for (int n = 0; n < NK; ++n)
                vv[n] = *(const float2*)(Vb + (size_t)jns[n] * NOUT + (l << 1));
#pragma unroll
            for (int n = 0; n < NK; ++n) {
                mv0 = fmaxf(mv0, vv[n].x);
                mv1 = fmaxf(mv1, vv[n].y);
            }
        }

        float2 uu = *(const float2*)(U + (size_t)gr * NOUT + (l << 1));
        float2 ov;
        ov.x = fmaxf(uu.x + mv0, 0.f);
        ov.y = fmaxf(uu.y + mv1, 0.f);
        *(float2*)(out + (size_t)gr * NOUT + (l << 1)) = ov;
    }
}

extern "C" void kernel_launch(void* const* d_in, const int* in_sizes, int n_in,
                              void* d_out, int out_size, void* d_ws, size_t ws_size,
                              hipStream_t stream) {
    const float* x    = (const float*)d_in[0];   // fp32 [32768][64]
    // d_in[1] = pos (unused), d_in[2] = batch (unused; uniform sorted segments)
    const float* W    = (const float*)d_in[3];   // fp32 [128][128]
    const float* bias = (const float*)d_in[4];   // fp32 [128]
    float* out = (float*)d_out;                  // fp32 [32768][128]

    float* sq = (float*)d_ws;                               // 32768 f32
    float* U  = sq + NBAT * NP;                             // 4.19M f32
    float* V  = U  + (size_t)NBAT * NP * NOUT;              // 4.19M f32
    unsigned short* xb16 = (unsigned short*)(V + (size_t)NBAT * NP * NOUT);

    prep_k<<<2048, 256, 0, stream>>>(x, W, bias, sq, U, V, xb16);

    const int lds_bytes = RT * HSTR * 2;                    // 65,664 B
    (void)hipFuncSetAttribute((const void*)knn_k,
                        hipFuncAttributeMaxDynamicSharedMemorySize, lds_bytes);
    knn_k<<<2048, 512, lds_bytes, stream>>>(x, xb16, sq, U, V, out);
}

// Round 11
// 159.480 us; speedup vs baseline: 1.3056x; 1.1324x over previous
//
#include <hip/hip_runtime.h>

typedef __bf16 bf16x8 __attribute__((ext_vector_type(8)));
typedef float  f32x4  __attribute__((ext_vector_type(4)));

#define NBAT 16
#define NP   2048
#define ND   64
#define NOUT 128
#define NK   16
#define RT   16            // rows per knn block
#define HSTR 2052          // d2 LDS row stride in halves (4104 B, 8B-aligned)

static __device__ __forceinline__ unsigned short f2bf(float f) {
    unsigned u = __float_as_uint(f);
    u += 0x7FFF + ((u >> 16) & 1);      // RNE
    return (unsigned short)(u >> 16);
}
static __device__ __forceinline__ int lanes_below(unsigned long long m) {
    return (int)__builtin_amdgcn_mbcnt_hi((unsigned)(m >> 32),
             __builtin_amdgcn_mbcnt_lo((unsigned)m, 0u));
}
static __device__ __forceinline__ unsigned long long umin64(unsigned long long a, unsigned long long b){ return a < b ? a : b; }
static __device__ __forceinline__ unsigned long long umax64(unsigned long long a, unsigned long long b){ return a < b ? b : a; }

// ascending bitonic sort of 128 u64 keys, element e = slot*64 + lane (rare path)
static __device__ __forceinline__ void bitonic_sort128_u64(unsigned long long &k0,
                                                           unsigned long long &k1, int lane) {
#pragma unroll
    for (int k = 2; k <= 64; k <<= 1) {
#pragma unroll
        for (int j = k >> 1; j >= 1; j >>= 1) {
            bool lower = ((lane & j) == 0);
            bool up0 = (k == 64) ? true  : ((lane & k) == 0);
            bool up1 = (k == 64) ? false : ((lane & k) == 0);
            unsigned long long o0 = __shfl_xor(k0, j, 64);
            k0 = (up0 == lower) ? umin64(k0, o0) : umax64(k0, o0);
            unsigned long long o1 = __shfl_xor(k1, j, 64);
            k1 = (up1 == lower) ? umin64(k1, o1) : umax64(k1, o1);
        }
    }
    { unsigned long long mn = umin64(k0, k1), mx = umax64(k0, k1); k0 = mn; k1 = mx; }
#pragma unroll
    for (int j = 32; j >= 1; j >>= 1) {
        bool lower = ((lane & j) == 0);
        unsigned long long o0 = __shfl_xor(k0, j, 64);
        k0 = lower ? umin64(k0, o0) : umax64(k0, o0);
        unsigned long long o1 = __shfl_xor(k1, j, 64);
        k1 = lower ? umin64(k1, o1) : umax64(k1, o1);
    }
}

// fp64-exact squared distance, rounded to fp32
static __device__ __forceinline__ float
refine_d(const float* __restrict__ x, int gr, int gcbase, int jc) {
    const float* xr = x + (size_t)gr * ND;
    const float* xc = x + (size_t)(gcbase + jc) * ND;
    double s0 = 0.0, s1 = 0.0;
#pragma unroll
    for (int k8 = 0; k8 < 8; ++k8) {
        float4 a = *(const float4*)(xr + k8 * 8);
        float4 b = *(const float4*)(xc + k8 * 8);
        float4 a2 = *(const float4*)(xr + k8 * 8 + 4);
        float4 b2 = *(const float4*)(xc + k8 * 8 + 4);
        double e0 = (double)a.x - (double)b.x;
        double e1 = (double)a.y - (double)b.y;
        double e2 = (double)a.z - (double)b.z;
        double e3 = (double)a.w - (double)b.w;
        s0 = fma(e0, e0, s0); s0 = fma(e1, e1, s0);
        s0 = fma(e2, e2, s0); s0 = fma(e3, e3, s0);
        double f0 = (double)a2.x - (double)b2.x;
        double f1 = (double)a2.y - (double)b2.y;
        double f2 = (double)a2.z - (double)b2.z;
        double f3 = (double)a2.w - (double)b2.w;
        s1 = fma(f0, f0, s1); s1 = fma(f1, f1, s1);
        s1 = fma(f2, f2, s1); s1 = fma(f3, f3, s1);
    }
    return (float)(s0 + s1);
}

// split fp32 x8 -> hi/lo bf16x8 (hi = RNE(f); lo = RNE(f - hi); f-hi exact)
static __device__ __forceinline__ void cvt_hilo(const float* __restrict__ p,
                                                bf16x8 &hi, bf16x8 &lo) {
    float4 a = *(const float4*)p, b = *(const float4*)(p + 4);
    float f[8] = {a.x, a.y, a.z, a.w, b.x, b.y, b.z, b.w};
#pragma unroll
    for (int i = 0; i < 8; ++i) {
        __bf16 h = (__bf16)f[i];
        hi[i] = h;
        lo[i] = (__bf16)(f[i] - (float)h);
    }
}

// ---------------------------------------------------------------------------
// prep (LDS-free, MFMA): sq (fp64-acc), xb16 (bf16 copy), U=(W1-W2)x+b, V=W2x.
// grid 512 x 256; each block 4 row-tiles of 16; W frags hoisted across tiles.
// ---------------------------------------------------------------------------
__global__ void __launch_bounds__(256)
prep_k(const float* __restrict__ x,     // [32768][64]
       const float* __restrict__ W,     // [128][128] (cols 0..63 = W1, 64..127 = W2)
       const float* __restrict__ bias,  // [128]
       float* __restrict__ sq, float* __restrict__ U,
       float* __restrict__ V,  unsigned short* __restrict__ xb16)
{
    const int blk = blockIdx.x, tid = threadIdx.x;
    const int R0b = blk * 64;
    const int w  = tid >> 6, l = tid & 63;
    const int l15 = l & 15, lg = l >> 4, kc = lg * 8;

    // hoisted W fragments: per wave o-tiles {w, w+4}; pos = {W1k0,W1k1,W2k0,W2k1}
    bf16x8 wh[2][4], wl[2][4];
#pragma unroll
    for (int tt = 0; tt < 2; ++tt) {
        const float* wb = W + (size_t)((w + tt * 4) * 16 + l15) * (2 * ND) + kc;
#pragma unroll
        for (int p = 0; p < 4; ++p)
            cvt_hilo(wb + p * 32, wh[tt][p], wl[tt][p]);
    }
    const int o0a = w * 16 + lg * 4;          // tt=0 channel base
    const int o0b = (w + 4) * 16 + lg * 4;    // tt=1 channel base
    float4 boa = *(const float4*)(bias + o0a);
    float4 bob = *(const float4*)(bias + o0b);

#pragma unroll 1
    for (int s4 = 0; s4 < 4; ++s4) {
        const int R0 = R0b + s4 * 16;

        // bf16 copy of x
        {
            int r = tid >> 4, c = (tid & 15) * 4;
            float4 v = *(const float4*)(x + (size_t)(R0 + r) * ND + c);
            ushort4 hb;
            hb.x = f2bf(v.x); hb.y = f2bf(v.y); hb.z = f2bf(v.z); hb.w = f2bf(v.w);
            *(ushort4*)(xb16 + (size_t)(R0 + r) * ND + c) = hb;
        }
        // sq with fp64 accumulation (threads 0..127, 8 lanes per row)
        if (tid < 128) {
            int r = tid >> 3, seg = tid & 7;
            const float* p = x + (size_t)(R0 + r) * ND + seg * 8;
            float4 a = *(const float4*)(p);
            float4 b = *(const float4*)(p + 4);
            double s = (double)a.x * a.x + (double)a.y * a.y +
                       (double)a.z * a.z + (double)a.w * a.w +
                       (double)b.x * b.x + (double)b.y * b.y +
                       (double)b.z * b.z + (double)b.w * b.w;
            s += __shfl_xor(s, 1, 64);
            s += __shfl_xor(s, 2, 64);
            s += __shfl_xor(s, 4, 64);
            if (seg == 0) sq[R0 + r] = (float)s;
        }

        // B-frags: X rows hi/lo, K-tiles 0 and 1
        const float* xr = x + (size_t)(R0 + l15) * ND + kc;
        bf16x8 bh0, bl0, bh1, bl1;
        cvt_hilo(xr,      bh0, bl0);
        cvt_hilo(xr + 32, bh1, bl1);

#pragma unroll
        for (int tt = 0; tt < 2; ++tt) {
            f32x4 accP = {0.f, 0.f, 0.f, 0.f};
            f32x4 accV = {0.f, 0.f, 0.f, 0.f};
            accP = __builtin_amdgcn_mfma_f32_16x16x32_bf16(wh[tt][0], bh0, accP, 0, 0, 0);
            accP = __builtin_amdgcn_mfma_f32_16x16x32_bf16(wh[tt][0], bl0, accP, 0, 0, 0);
            accP = __builtin_amdgcn_mfma_f32_16x16x32_bf16(wl[tt][0], bh0, accP, 0, 0, 0);
            accP = __builtin_amdgcn_mfma_f32_16x16x32_bf16(wh[tt][1], bh1, accP, 0, 0, 0);
            accP = __builtin_amdgcn_mfma_f32_16x16x32_bf16(wh[tt][1], bl1, accP, 0, 0, 0);
            accP = __builtin_amdgcn_mfma_f32_16x16x32_bf16(wl[tt][1], bh1, accP, 0, 0, 0);
            accV = __builtin_amdgcn_mfma_f32_16x16x32_bf16(wh[tt][2], bh0, accV, 0, 0, 0);
            accV = __builtin_amdgcn_mfma_f32_16x16x32_bf16(wh[tt][2], bl0, accV, 0, 0, 0);
            accV = __builtin_amdgcn_mfma_f32_16x16x32_bf16(wl[tt][2], bh0, accV, 0, 0, 0);
            accV = __builtin_amdgcn_mfma_f32_16x16x32_bf16(wh[tt][3], bh1, accV, 0, 0, 0);
            accV = __builtin_amdgcn_mfma_f32_16x16x32_bf16(wh[tt][3], bl1, accV, 0, 0, 0);
            accV = __builtin_amdgcn_mfma_f32_16x16x32_bf16(wl[tt][3], bh1, accV, 0, 0, 0);

            const int o0 = tt ? o0b : o0a;
            float4 bo = tt ? bob : boa;
            float4 uu, vv;
            uu.x = accP[0] - accV[0] + bo.x;  vv.x = accV[0];
            uu.y = accP[1] - accV[1] + bo.y;  vv.y = accV[1];
            uu.z = accP[2] - accV[2] + bo.z;  vv.z = accV[2];
            uu.w = accP[3] - accV[3] + bo.w;  vv.w = accV[3];
            *(float4*)(U + (size_t)(R0 + l15) * NOUT + o0) = uu;
            *(float4*)(V + (size_t)(R0 + l15) * NOUT + o0) = vv;
        }
    }
}

// ---------------------------------------------------------------------------
// knn + aggregate. grid 2048 x 1024 (16 waves), RT=16, 2 blocks/CU
// (32 waves/CU). Phase 1: bf16 MFMA Gram -> fp16 d2 tile (66 KB LDS),
// 8 col-tiles/wave. Phase 2: ONE row per wave: tau via 16-rd ballot radix;
// scan compaction; fp64 refine; T via 31-rd ballot radix; exact-16 winner
// mask; 16 in-flight V loads. sort128_u64 fallback (>64 survivors or
// ambiguous fp32 tie).
// ---------------------------------------------------------------------------
__global__ void __launch_bounds__(1024, 2)
knn_k(const float* __restrict__ x,             // [32768][64] fp32 (refine)
      const unsigned short* __restrict__ xb16, // [32768][64] bf16
      const float* __restrict__ sq,
      const float* __restrict__ U,
      const float* __restrict__ V,
      float* __restrict__ out)
{
    extern __shared__ __align__(16) unsigned char smem[];
    unsigned short* d2h = (unsigned short*)smem;   // [RT][HSTR] halves
    __shared__ unsigned short cbuf[16][128];

    // XCD-aware decode: q%8 = XCD; each XCD gets 2 full batches
    const int q   = blockIdx.x;
    const int xcd = q & 7;
    const int k_  = q >> 3;               // 0..255
    const int bb  = xcd * 2 + (k_ >> 7);  // batch
    const int rt  = k_ & 127;             // row tile within batch
    const int R0l = rt * RT;
    const int R0g = bb * NP + R0l;
    const int tid = threadIdx.x;
    const int w   = tid >> 6;             // 0..15
    const int l   = tid & 63;
    const int l15 = l & 15, lg = l >> 4, kc = lg * 8;

    // N-operand fragments: the 16 block rows
    const unsigned short* nr = xb16 + (size_t)(R0g + l15) * ND + kc;
    bf16x8 n0 = *(const bf16x8*)(nr);
    bf16x8 n1 = *(const bf16x8*)(nr + 32);
    const float sqrow = sq[R0g + l15];

    const unsigned short* xbb = xb16 + (size_t)bb * NP * ND;
    const float* sqb = sq + bb * NP;

    // ---- Phase 1: MFMA Gram -> fp16 d2 in LDS (8 col-tiles per wave) ----
#pragma unroll 4
    for (int t = 0; t < 8; ++t) {
        const int cb = (w * 8 + t) * 16;
        const unsigned short* ar = xbb + (size_t)(cb + l15) * ND + kc;
        bf16x8 a0 = *(const bf16x8*)(ar);
        bf16x8 a1 = *(const bf16x8*)(ar + 32);
        f32x4 acc = {0.f, 0.f, 0.f, 0.f};
        acc = __builtin_amdgcn_mfma_f32_16x16x32_bf16(a0, n0, acc, 0, 0, 0);
        acc = __builtin_amdgcn_mfma_f32_16x16x32_bf16(a1, n1, acc, 0, 0, 0);
        // D[batch col][block row]: lane holds block row = l15, cols jb4..jb4+3
        const int jb4 = cb + lg * 4;
        float4 sq4 = *(const float4*)(sqb + jb4);
        unsigned short hh[4];
#pragma unroll
        for (int i = 0; i < 4; ++i) {
            float sqc = (i == 0) ? sq4.x : (i == 1) ? sq4.y : (i == 2) ? sq4.z : sq4.w;
            float d2 = fmaxf(fmaf(-2.f, acc[i], sqrow + sqc), 0.f);
            unsigned short h = __builtin_bit_cast(unsigned short, (_Float16)d2);
            if (R0l + l15 == jb4 + i) h = 0x7C00;   // self -> +inf
            hh[i] = h;
        }
        ushort4 hv; hv.x = hh[0]; hv.y = hh[1]; hv.z = hh[2]; hv.w = hh[3];
        *(ushort4*)(d2h + (size_t)l15 * HSTR + jb4) = hv;
    }
    __syncthreads();

    // ---- Phase 2: ONE row per wave ----
    const int gcbase = bb * NP;
    {
        const int r  = w;
        const int gr = R0g + r;
        const unsigned short* rowp = d2h + (size_t)r * HSTR;

        // load 32 fp16 values; slot (s,i) <-> col j = 256*s + 4*l + i
        unsigned int h[32];
#pragma unroll
        for (int s = 0; s < 8; ++s) {
            ushort4 hv = *(const ushort4*)(rowp + (s * 64 + l) * 4);
            h[s*4+0] = hv.x; h[s*4+1] = hv.y; h[s*4+2] = hv.z; h[s*4+3] = hv.w;
        }
        unsigned int mnh = h[0];
#pragma unroll
        for (int i = 1; i < 32; ++i) mnh = (h[i] < mnh) ? h[i] : mnh;

        // tau = 16th smallest of the 64 lane-minima: ballot radix (0 DS ops)
        unsigned int t16 = 0;
#pragma unroll
        for (int b = 15; b >= 0; --b) {
            unsigned int cand = t16 | (1u << b);
            int c = __popcll(__ballot(mnh < cand));
            if (c < 16) t16 = cand;
        }
        // widen by +1.0 ABSOLUTE (bf16 Gram noise, 11 sigma) + 1 ulp
        float tf = (float)__builtin_bit_cast(_Float16, (unsigned short)t16) + 1.0f;
        unsigned int tauh =
            (unsigned int)__builtin_bit_cast(unsigned short, (_Float16)tf) + 1u;

        // per-lane survivor pack (slot ids, 5 bits each, up to 4)
        unsigned int packed = 0; int cnt = 0;
#pragma unroll
        for (int i = 0; i < 32; ++i) {
            if (h[i] <= tauh) {
                if (cnt < 4) packed |= (unsigned)i << (5 * cnt);
                ++cnt;
            }
        }
        bool ovf = (__ballot(cnt > 4) != 0ull);   // wave-uniform

        cbuf[w][l]      = 0xFFFF;
        cbuf[w][64 + l] = 0xFFFF;
        int total;
        if (!ovf) {
            // exclusive scan of cnt (6 shfl_up)
            int inc = cnt;
#pragma unroll
            for (int off = 1; off < 64; off <<= 1) {
                int nv = __shfl_up(inc, off, 64);
                if (l >= off) inc += nv;
            }
            int excl = inc - cnt;
            total = __shfl(inc, 63, 64);
#pragma unroll
            for (int kk = 0; kk < 4; ++kk) {
                if (kk < cnt && excl + kk < 128) {
                    int slot = (packed >> (5 * kk)) & 31;
                    cbuf[w][excl + kk] =
                        (unsigned short)(256 * (slot >> 2) + 4 * l + (slot & 3));
                }
            }
        } else {
            // rare slow path: serial ballot compaction
            int base = 0;
#pragma unroll 1
            for (int i = 0; i < 32; ++i) {
                bool pred = (h[i] <= tauh);
                unsigned long long m = __ballot(pred);
                int pos = base + lanes_below(m);
                if (pred && pos < 128)
                    cbuf[w][pos] = (unsigned short)(256 * (i >> 2) + 4 * l + (i & 3));
                base += __popcll(m);
            }
            total = base;
        }
        asm volatile("s_waitcnt lgkmcnt(0)" ::: "memory");
        __builtin_amdgcn_sched_barrier(0);

        const float* Vb = V + (size_t)bb * NP * NOUT;
        float mv0 = -1e30f, mv1 = -1e30f;
        int jc = cbuf[w][l];

        bool fast = (total <= 64);
        unsigned long long win_m = 0ull;
        if (fast) {
            unsigned int dbits = 0xFFFFFFFFu;
            if (jc != 0xFFFF)
                dbits = __float_as_uint(refine_d(x, gr, gcbase, jc));

            // T = 16th smallest refined value: 31-round ballot radix (0 DS)
            unsigned int T = 0;
#pragma unroll
            for (int b = 30; b >= 0; --b) {
                unsigned int cand = T | (1u << b);
                int c = __popcll(__ballot(dbits < cand));
                if (c < 16) T = cand;
            }
            unsigned long long less_m = __ballot(dbits < T);
            int c_less = __popcll(less_m);
            int need = 16 - c_less;
            unsigned long long tie_m = __ballot(dbits == T);
            if (__popcll(tie_m) == need) {
                win_m = less_m | tie_m;           // exactly 16, unambiguous
            } else {
                fast = false;                      // ambiguous fp32 tie: exact path
            }
        }

        if (fast) {
            int jns[NK];
            unsigned long long mm = win_m;
#pragma unroll
            for (int n = 0; n < NK; ++n) {
                int ln = __ffsll((long long)mm) - 1;
                jns[n] = __builtin_amdgcn_readlane(jc, ln);
                mm &= mm - 1;
            }
            float2 vv[NK];
#pragma unroll
            for (int n = 0; n < NK; ++n)
                vv[n] = *(const float2*)(Vb + (size_t)jns[n] * NOUT + (l << 1));
#pragma unroll
            for (int n = 0; n < NK; ++n) {
                mv0 = fmaxf(mv0, vv[n].x);
                mv1 = fmaxf(mv1, vv[n].y);
            }
        } else {
            // exact fallback: sort refined keys with index tiebreak
            int jc1 = cbuf[w][64 + l];
            unsigned long long rk0 = (jc != 0xFFFF)
                ? ((((unsigned long long)__float_as_uint(refine_d(x, gr, gcbase, jc))) << 11) | (unsigned)jc)
                : ~0ull;
            unsigned long long rk1 = (jc1 != 0xFFFF)
                ? ((((unsigned long long)__float_as_uint(refine_d(x, gr, gcbase, jc1))) << 11) | (unsigned)jc1)
                : ~0ull;
            bitonic_sort128_u64(rk0, rk1, l);
            int nbr = (int)(rk0 & 2047u);
            int jns[NK];
#pragma unroll
            for (int n = 0; n < NK; ++n)
                jns[n] = __builtin_amdgcn_readlane(nbr, n);
            float2 vv[NK];
#pragma unroll
            for (int n = 0; n < NK; ++n)
                vv[n] = *(const float2*)(Vb + (size_t)jns[n] * NOUT + (l << 1));
#pragma unroll
            for (int n = 0; n < NK; ++n) {
                mv0 = fmaxf(mv0, vv[n].x);
                mv1 = fmaxf(mv1, vv[n].y);
            }
        }

        float2 uu = *(const float2*)(U + (size_t)gr * NOUT + (l << 1));
        float2 ov;
        ov.x = fmaxf(uu.x + mv0, 0.f);
        ov.y = fmaxf(uu.y + mv1, 0.f);
        *(float2*)(out + (size_t)gr * NOUT + (l << 1)) = ov;
    }
}

extern "C" void kernel_launch(void* const* d_in, const int* in_sizes, int n_in,
                              void* d_out, int out_size, void* d_ws, size_t ws_size,
                              hipStream_t stream) {
    const float* x    = (const float*)d_in[0];   // fp32 [32768][64]
    // d_in[1] = pos (unused), d_in[2] = batch (unused; uniform sorted segments)
    const float* W    = (const float*)d_in[3];   // fp32 [128][128]
    const float* bias = (const float*)d_in[4];   // fp32 [128]
    float* out = (float*)d_out;                  // fp32 [32768][128]

    float* sq = (float*)d_ws;                               // 32768 f32
    float* U  = sq + NBAT * NP;                             // 4.19M f32
    float* V  = U  + (size_t)NBAT * NP * NOUT;              // 4.19M f32
    unsigned short* xb16 = (unsigned short*)(V + (size_t)NBAT * NP * NOUT);

    prep_k<<<512, 256, 0, stream>>>(x, W, bias, sq, U, V, xb16);

    const int lds_bytes = RT * HSTR * 2;                    // 65,664 B
    (void)hipFuncSetAttribute((const void*)knn_k,
                        hipFuncAttributeMaxDynamicSharedMemorySize, lds_bytes);
    knn_k<<<2048, 1024, lds_bytes, stream>>>(x, xb16, sq, U, V, out);
}